// Round 5
// baseline (372.434 us; speedup 1.0000x reference)
//
#include <hip/hip_runtime.h>
#include <hip/hip_cooperative_groups.h>
#include <math.h>

namespace cg = cooperative_groups;

#define NB 4
#define NN 512

// ---------------- kA: ha = X@Wa + b1, hb = X@Wb ; zero ru ----------------
__global__ void kA(const float* __restrict__ X, const float* __restrict__ W1,
                   const float* __restrict__ b1, float* __restrict__ ha,
                   float* __restrict__ hb, float* __restrict__ ru) {
  int b = blockIdx.y, n0 = blockIdx.x * 8;
  __shared__ float xs[8][128];
  int t = threadIdx.x;  // 128 threads
  for (int q = t; q < 1024; q += 128) {
    int r = q >> 7, f = q & 127;
    xs[r][f] = X[(size_t)(b * NN + n0 + r) * 128 + f];
  }
  int flat = b * 64 + blockIdx.x;
  if (flat < 16) ru[flat * 128 + t] = 0.f;
  __syncthreads();
  float accA[8] = {0,0,0,0,0,0,0,0}, accB[8] = {0,0,0,0,0,0,0,0};
  for (int f = 0; f < 128; ++f) {
    float wa = W1[f * 128 + t];
    float wb = W1[(128 + f) * 128 + t];
#pragma unroll
    for (int r = 0; r < 8; ++r) {
      accA[r] = fmaf(xs[r][f], wa, accA[r]);
      accB[r] = fmaf(xs[r][f], wb, accB[r]);
    }
  }
  float b1v = b1[t];
#pragma unroll
  for (int r = 0; r < 8; ++r) {
    ha[(size_t)(b * NN + n0 + r) * 128 + t] = accA[r] + b1v;
    hb[(size_t)(b * NN + n0 + r) * 128 + t] = accB[r];
  }
}

// ------- kB: K = exp(-5*cost), cost = relu(ha_i+hb_j+dist*wd)@W2 + b2 ----
__global__ void kB(const float* __restrict__ ha, const float* __restrict__ hb,
                   const float* __restrict__ coords, const float* __restrict__ W1,
                   const float* __restrict__ W2, const float* __restrict__ b2,
                   float* __restrict__ Km, float* __restrict__ ru) {
  int b = blockIdx.z, i0 = blockIdx.y * 32, j0 = blockIdx.x * 32;
  __shared__ alignas(16) float As[32][132];
  __shared__ alignas(16) float Bs[32][132];
  __shared__ alignas(16) float wd[128];
  __shared__ alignas(16) float w2[128];
  __shared__ float ci[32][3], cj[32][3];
  int t = threadIdx.x;  // 256
  for (int q = t; q < 1024; q += 256) {
    int r = q >> 5, c = (q & 31) * 4;
    *(float4*)&As[r][c] = *(const float4*)&ha[(size_t)(b * NN + i0 + r) * 128 + c];
    *(float4*)&Bs[r][c] = *(const float4*)&hb[(size_t)(b * NN + j0 + r) * 128 + c];
  }
  if (t < 128) { wd[t] = W1[256 * 128 + t]; w2[t] = W2[t]; }
  if (t < 96) ((float*)ci)[t] = coords[(size_t)(b * NN + i0) * 3 + t];
  else if (t < 192) ((float*)cj)[t - 96] = coords[(size_t)(b * NN + j0) * 3 + (t - 96)];
  __syncthreads();
  int tx = t & 15, ty = t >> 4;
  int ia = 2 * ty, ib = ia + 1, ja = tx, jb = tx + 16;
  float d00, d01, d10, d11;
  {
    float ax = ci[ia][0], ay = ci[ia][1], az = ci[ia][2];
    float bx = ci[ib][0], by = ci[ib][1], bz = ci[ib][2];
    float cx0 = cj[ja][0], cy0 = cj[ja][1], cz0 = cj[ja][2];
    float cx1 = cj[jb][0], cy1 = cj[jb][1], cz1 = cj[jb][2];
    float dx, dy, dz;
    dx = ax - cx0; dy = ay - cy0; dz = az - cz0;
    d00 = sqrtf(fmaxf(dx * dx + dy * dy + dz * dz, 0.f));
    dx = ax - cx1; dy = ay - cy1; dz = az - cz1;
    d01 = sqrtf(fmaxf(dx * dx + dy * dy + dz * dz, 0.f));
    dx = bx - cx0; dy = by - cy0; dz = bz - cz0;
    d10 = sqrtf(fmaxf(dx * dx + dy * dy + dz * dz, 0.f));
    dx = bx - cx1; dy = by - cy1; dz = bz - cz1;
    d11 = sqrtf(fmaxf(dx * dx + dy * dy + dz * dz, 0.f));
  }
  float a00 = 0, a01 = 0, a10 = 0, a11 = 0;
  for (int k = 0; k < 128; k += 4) {
    float4 A0 = *(float4*)&As[ia][k];
    float4 A1 = *(float4*)&As[ib][k];
    float4 B0 = *(float4*)&Bs[ja][k];
    float4 B1 = *(float4*)&Bs[jb][k];
    float4 W = *(float4*)&wd[k];
    float4 V = *(float4*)&w2[k];
#pragma unroll
    for (int kk = 0; kk < 4; ++kk) {
      float av = ((float*)&A0)[kk], av1 = ((float*)&A1)[kk];
      float bv = ((float*)&B0)[kk], bv1 = ((float*)&B1)[kk];
      float wv = ((float*)&W)[kk], vv = ((float*)&V)[kk];
      float t00 = fmaxf(fmaf(d00, wv, av + bv), 0.f);
      float t01 = fmaxf(fmaf(d01, wv, av + bv1), 0.f);
      float t10 = fmaxf(fmaf(d10, wv, av1 + bv), 0.f);
      float t11 = fmaxf(fmaf(d11, wv, av1 + bv1), 0.f);
      a00 = fmaf(t00, vv, a00);
      a01 = fmaf(t01, vv, a01);
      a10 = fmaf(t10, vv, a10);
      a11 = fmaf(t11, vv, a11);
    }
  }
  float b2v = b2[0];
  float k00 = __expf(-5.0f * (a00 + b2v));
  float k01 = __expf(-5.0f * (a01 + b2v));
  float k10 = __expf(-5.0f * (a10 + b2v));
  float k11 = __expf(-5.0f * (a11 + b2v));
  size_t r0 = (size_t)(b * NN + i0 + ia) * NN + j0;
  size_t r1 = (size_t)(b * NN + i0 + ib) * NN + j0;
  Km[r0 + ja] = k00; Km[r0 + jb] = k01;
  Km[r1 + ja] = k10; Km[r1 + jb] = k11;
  float s0 = k00 + k01, s1 = k10 + k11;
#pragma unroll
  for (int off = 1; off < 16; off <<= 1) {
    s0 += __shfl_xor(s0, off);
    s1 += __shfl_xor(s1, off);
  }
  if (tx == 0) {
    atomicAdd(&ru[b * NN + i0 + ia], s0);
    atomicAdd(&ru[b * NN + i0 + ib], s1);
  }
}

// ------- kSink: cooperative fused Sinkhorn (kCcol + 9 iters + adj) -------
// grid (32, 4): block (ic, b) owns rows ic*16..+16 of batch b.
// ru holds K row sums (u1 denominators) from kB.
__global__ __launch_bounds__(512) void kSink(const float* __restrict__ Km,
                                             const float* __restrict__ ru,
                                             float* __restrict__ rvpA,
                                             float* __restrict__ rvpB,
                                             float* __restrict__ out) {
  cg::grid_group grid = cg::this_grid();
  int ic = blockIdx.x, b = blockIdx.y;
  int t = threadIdx.x;  // 512
  int r0 = ic * 16;
  __shared__ float vinv[512];
  __shared__ float uinv[16];
  const float* Kcp = Km + (size_t)(b * NN + r0) * NN + t;
  // step 0: uinv = u1 for my rows; col partials -> rvpA  (completes iter 1)
  if (t < 16) uinv[t] = 1.0f / ru[b * NN + r0 + t];
  __syncthreads();
  {
    float acc = 0.f;
#pragma unroll
    for (int ii = 0; ii < 16; ++ii) acc = fmaf(Kcp[(size_t)ii * NN], uinv[ii], acc);
    rvpA[((size_t)b * 32 + ic) * NN + t] = acc;
  }
  grid.sync();
  const float* rsrc = rvpA;
  float* rdst = rvpB;
  for (int it = 0; it < 9; ++it) {
    // vinv from all 32 partials of this batch
    {
      const float* rp = rsrc + (size_t)b * 32 * NN + t;
      float s = 0.f;
#pragma unroll 8
      for (int q = 0; q < 32; ++q) s += rp[(size_t)q * NN];
      vinv[t] = 1.0f / s;
    }
    __syncthreads();
    // row pass: wave w handles rows 2w, 2w+1
    int w = t >> 6, l = t & 63;
#pragma unroll
    for (int m = 0; m < 2; ++m) {
      int r = r0 + w * 2 + m;
      const float* Kp = Km + (size_t)(b * NN + r) * NN;
      float acc = 0.f;
#pragma unroll
      for (int mm = 0; mm < 8; ++mm) acc = fmaf(Kp[l + 64 * mm], vinv[l + 64 * mm], acc);
#pragma unroll
      for (int off = 1; off < 64; off <<= 1) acc += __shfl_xor(acc, off);
      if (l == 0) uinv[w * 2 + m] = 1.0f / acc;
    }
    __syncthreads();
    // col partials with new uinv
    {
      float acc = 0.f;
#pragma unroll
      for (int ii = 0; ii < 16; ++ii) acc = fmaf(Kcp[(size_t)ii * NN], uinv[ii], acc);
      rdst[((size_t)b * 32 + ic) * NN + t] = acc;
    }
    grid.sync();
    float* tmp = (float*)rsrc; rsrc = rdst; rdst = tmp;
  }
  // epilogue: adj = uinv_i * K * vinv_j  (u10, v10)
  {
    const float* rp = rsrc + (size_t)b * 32 * NN + t;
    float s = 0.f;
#pragma unroll 8
    for (int q = 0; q < 32; ++q) s += rp[(size_t)q * NN];
    float vj = 1.0f / s;
    const float* Kp = Km + (size_t)(b * NN + r0) * NN + t;
    float* op = out + (size_t)(b * NN + r0) * NN + t;
#pragma unroll 4
    for (int m = 0; m < 16; ++m)
      op[(size_t)m * NN] = Kp[(size_t)m * NN] * uinv[m] * vj;
  }
}

// ------- kG1: xw = x @ Wg[l]  (2048x512, K=128) ---------------------------
__global__ void kG1(const float* __restrict__ x, const float* __restrict__ Wg,
                    float* __restrict__ xw) {
  int b = blockIdx.y, n0 = blockIdx.x * 8;
  __shared__ float xs[8][128];
  int t = threadIdx.x;  // 256
  for (int q = t; q < 1024; q += 256) {
    int r = q >> 7, f = q & 127;
    xs[r][f] = x[(size_t)(b * NN + n0 + r) * 128 + f];
  }
  __syncthreads();
  int c0 = t, c1 = t + 256;
  float acc0[8] = {0,0,0,0,0,0,0,0}, acc1[8] = {0,0,0,0,0,0,0,0};
  for (int f = 0; f < 128; ++f) {
    float w0 = Wg[f * 512 + c0], w1 = Wg[f * 512 + c1];
#pragma unroll
    for (int r = 0; r < 8; ++r) {
      float xv = xs[r][f];
      acc0[r] = fmaf(xv, w0, acc0[r]);
      acc1[r] = fmaf(xv, w1, acc1[r]);
    }
  }
#pragma unroll
  for (int r = 0; r < 8; ++r) {
    xw[(size_t)(b * NN + n0 + r) * 512 + c0] = acc0[r];
    xw[(size_t)(b * NN + n0 + r) * 512 + c1] = acc1[r];
  }
}

// ------- kG1b: s_src/s_dst (transposed layout [b*4+h][n]) ----------------
__global__ void kG1b(const float* __restrict__ xw, const float* __restrict__ asrc,
                     const float* __restrict__ adst, float* __restrict__ ssT,
                     float* __restrict__ sdT) {
  int n = blockIdx.x, b = blockIdx.y;
  int t = threadIdx.x;  // 128
  const float* row = xw + (size_t)(b * NN + n) * 512;
  float ps[4], pd[4];
#pragma unroll
  for (int q = 0; q < 4; ++q) {
    int c = q * 128 + t;
    float v = row[c];
    ps[q] = v * asrc[c];
    pd[q] = v * adst[c];
  }
#pragma unroll
  for (int off = 1; off < 64; off <<= 1) {
#pragma unroll
    for (int q = 0; q < 4; ++q) {
      ps[q] += __shfl_xor(ps[q], off);
      pd[q] += __shfl_xor(pd[q], off);
    }
  }
  __shared__ float part[2][8];
  int w = t >> 6, l = t & 63;
  if (l == 0) {
#pragma unroll
    for (int q = 0; q < 4; ++q) { part[w][q] = ps[q]; part[w][4 + q] = pd[q]; }
  }
  __syncthreads();
  if (t < 8) {
    float s = part[0][t] + part[1][t];
    int h = t & 3;
    if (t < 4) ssT[(size_t)(b * 4 + h) * 512 + n] = s;
    else       sdT[(size_t)(b * 4 + h) * 512 + n] = s;
  }
}

// ------- kG2t: per (b,h,8-row tile): P in LDS + 4-way j-split PV ---------
#define PLD8 520
__global__ __launch_bounds__(512) void kG2t(const float* __restrict__ xw,
                                            const float* __restrict__ ssT,
                                            const float* __restrict__ sdT,
                                            float* __restrict__ partial) {
  int b = blockIdx.z, h = blockIdx.y, i0 = blockIdx.x * 8;
  int bh = b * 4 + h;
  __shared__ float ss[512];
  __shared__ alignas(16) float pl[8][PLD8];   // reused as reduce scratch
  __shared__ float sdl[8], mxl[8], idl[8], smaxsh[8];
  int t = threadIdx.x;  // 512
  {
    float v = ssT[(size_t)bh * 512 + t];
    ss[t] = v;
#pragma unroll
    for (int off = 1; off < 64; off <<= 1) v = fmaxf(v, __shfl_xor(v, off));
    if ((t & 63) == 0) smaxsh[t >> 6] = v;
  }
  __syncthreads();
  if (t < 8) {
    float m = smaxsh[0];
#pragma unroll
    for (int q = 1; q < 8; ++q) m = fmaxf(m, smaxsh[q]);
    float sdv = sdT[(size_t)bh * 512 + i0 + t];
    sdl[t] = sdv;
    float mm = sdv + m;
    mxl[t] = (mm >= 0.f) ? mm : 0.2f * mm;
  }
  __syncthreads();
  {
    int il = t >> 6, jq = t & 63;
    float mx = mxl[il], sdv = sdl[il];
    float den = 0.f;
#pragma unroll
    for (int jj = 0; jj < 8; ++jj) {
      int j = jj * 64 + jq;
      float e = sdv + ss[j];
      e = (e >= 0.f) ? e : 0.2f * e;
      float pe = __expf(e - mx);
      pl[il][j] = pe;
      den += pe;
    }
#pragma unroll
    for (int off = 1; off < 64; off <<= 1) den += __shfl_xor(den, off);
    if (jq == 0) idl[il] = 1.0f / (4.0f * den);
  }
  __syncthreads();
  int fq = t & 31, rr = (t >> 5) & 3, jh = t >> 7;
  const float* xp = xw + (size_t)(b * NN) * 512 + h * 128 + fq * 4;
  float4 a0 = {0,0,0,0}, a1 = {0,0,0,0};
  int jbase = jh * 128;
#pragma unroll 4
  for (int jj = 0; jj < 128; jj += 2) {
    int j = jbase + jj;
    float4 xv0 = *(const float4*)&xp[(size_t)j * 512];
    float4 xv1 = *(const float4*)&xp[(size_t)(j + 1) * 512];
    float2 p0 = *(const float2*)&pl[rr][j];
    float2 p1 = *(const float2*)&pl[rr + 4][j];
    a0.x = fmaf(p0.x, xv0.x, a0.x); a0.y = fmaf(p0.x, xv0.y, a0.y);
    a0.z = fmaf(p0.x, xv0.z, a0.z); a0.w = fmaf(p0.x, xv0.w, a0.w);
    a1.x = fmaf(p1.x, xv0.x, a1.x); a1.y = fmaf(p1.x, xv0.y, a1.y);
    a1.z = fmaf(p1.x, xv0.z, a1.z); a1.w = fmaf(p1.x, xv0.w, a1.w);
    a0.x = fmaf(p0.y, xv1.x, a0.x); a0.y = fmaf(p0.y, xv1.y, a0.y);
    a0.z = fmaf(p0.y, xv1.z, a0.z); a0.w = fmaf(p0.y, xv1.w, a0.w);
    a1.x = fmaf(p1.y, xv1.x, a1.x); a1.y = fmaf(p1.y, xv1.y, a1.y);
    a1.z = fmaf(p1.y, xv1.z, a1.z); a1.w = fmaf(p1.y, xv1.w, a1.w);
  }
  __syncthreads();
  float4* sc4 = (float4*)pl;
  sc4[(rr * 32 + fq) + 256 * jh] = a0;
  sc4[((rr + 4) * 32 + fq) + 256 * jh] = a1;
  __syncthreads();
  if (t < 256) {
    int r = t >> 5, ff = t & 31;
    float4 u0 = sc4[(r * 32 + ff)];
    float4 u1 = sc4[(r * 32 + ff) + 256];
    float4 u2 = sc4[(r * 32 + ff) + 512];
    float4 u3 = sc4[(r * 32 + ff) + 768];
    float s0 = idl[r];
    float4 o;
    o.x = (u0.x + u1.x + u2.x + u3.x) * s0;
    o.y = (u0.y + u1.y + u2.y + u3.y) * s0;
    o.z = (u0.z + u1.z + u2.z + u3.z) * s0;
    o.w = (u0.w + u1.w + u2.w + u3.w) * s0;
    *(float4*)&partial[((size_t)bh * NN + i0 + r) * 128 + ff * 4] = o;
  }
}

// ------- kRed: xo[b,i,f] = sum_h partial[b,h,i,f] + bg[f] ----------------
__global__ void kRed(const float* __restrict__ partial, const float* __restrict__ bg,
                     float* __restrict__ xo) {
  int idx = blockIdx.x * 256 + threadIdx.x;  // float4 index, 65536 total
  int f4 = idx & 31;
  int rest = idx >> 5;           // b*512 + i
  int b = rest >> 9, i = rest & 511;
  const float* pp = partial + (((size_t)b * 4) * NN + i) * 128 + f4 * 4;
  float4 s = *(const float4*)pp;
  const float* p1 = pp + (size_t)NN * 128;
  const float* p2 = pp + (size_t)2 * NN * 128;
  const float* p3 = pp + (size_t)3 * NN * 128;
  float4 v1 = *(const float4*)p1, v2 = *(const float4*)p2, v3 = *(const float4*)p3;
  float4 bb = *(const float4*)&bg[f4 * 4];
  s.x += v1.x + v2.x + v3.x + bb.x;
  s.y += v1.y + v2.y + v3.y + bb.y;
  s.z += v1.z + v2.z + v3.z + bb.z;
  s.w += v1.w + v2.w + v3.w + bb.w;
  *(float4*)&xo[(size_t)rest * 128 + f4 * 4] = s;
}

// ------- kF: final_adj = sigmoid(x @ x^T) --------------------------------
__global__ void kF(const float* __restrict__ x, float* __restrict__ out) {
  int b = blockIdx.z, i0 = blockIdx.y * 32, j0 = blockIdx.x * 32;
  __shared__ alignas(16) float As[32][132];
  __shared__ alignas(16) float Bs[32][132];
  int t = threadIdx.x;  // 256
  for (int q = t; q < 1024; q += 256) {
    int r = q >> 5, c = (q & 31) * 4;
    *(float4*)&As[r][c] = *(const float4*)&x[(size_t)(b * NN + i0 + r) * 128 + c];
    *(float4*)&Bs[r][c] = *(const float4*)&x[(size_t)(b * NN + j0 + r) * 128 + c];
  }
  __syncthreads();
  int tx = t & 15, ty = t >> 4;
  int ia = 2 * ty, ib = ia + 1, ja = tx, jb = tx + 16;
  float a00 = 0, a01 = 0, a10 = 0, a11 = 0;
  for (int k = 0; k < 128; k += 4) {
    float4 A0 = *(float4*)&As[ia][k];
    float4 A1 = *(float4*)&As[ib][k];
    float4 B0 = *(float4*)&Bs[ja][k];
    float4 B1 = *(float4*)&Bs[jb][k];
#pragma unroll
    for (int kk = 0; kk < 4; ++kk) {
      float av = ((float*)&A0)[kk], av1 = ((float*)&A1)[kk];
      float bv = ((float*)&B0)[kk], bv1 = ((float*)&B1)[kk];
      a00 = fmaf(av, bv, a00);
      a01 = fmaf(av, bv1, a01);
      a10 = fmaf(av1, bv, a10);
      a11 = fmaf(av1, bv1, a11);
    }
  }
  size_t r0 = (size_t)(b * NN + i0 + ia) * NN + j0;
  size_t r1 = (size_t)(b * NN + i0 + ib) * NN + j0;
  out[r0 + ja] = 1.0f / (1.0f + __expf(-a00));
  out[r0 + jb] = 1.0f / (1.0f + __expf(-a01));
  out[r1 + ja] = 1.0f / (1.0f + __expf(-a10));
  out[r1 + jb] = 1.0f / (1.0f + __expf(-a11));
}

extern "C" void kernel_launch(void* const* d_in, const int* in_sizes, int n_in,
                              void* d_out, int out_size, void* d_ws, size_t ws_size,
                              hipStream_t stream) {
  (void)in_sizes; (void)n_in; (void)out_size; (void)ws_size;
  const float* X   = (const float*)d_in[0];
  const float* C   = (const float*)d_in[1];
  const float* W1  = (const float*)d_in[2];
  const float* b1  = (const float*)d_in[3];
  const float* W2  = (const float*)d_in[4];
  const float* b2  = (const float*)d_in[5];
  const float* Wg  = (const float*)d_in[6];
  const float* as_ = (const float*)d_in[7];
  const float* ad_ = (const float*)d_in[8];
  const float* bg  = (const float*)d_in[9];
  float* out = (float*)d_out;
  float* ws = (float*)d_ws;

  float* ha    = ws;                 // 262144
  float* hb    = ws + 262144;        // 262144
  float* Km    = ws + 524288;        // 1048576
  float* ru    = ws + 1572864;       // 2048
  float* xw    = ws + 1591296;       // 1048576
  float* ssT   = ws + 2639872;       // 8192
  float* sdT   = ws + 2648064;       // 8192
  float* x1    = ws + 2656256;       // 262144
  float* x2    = ws + 2918400;       // 262144
  float* rvpA  = ws + 3180544;       // 65536 (32 partials x 4 b x 512 j)
  float* rvpB  = ws + 3246080;       // 65536
  float* adj   = out + 1048576;
  float* partial = Km;               // alias: Km is dead after kSink

  kA<<<dim3(64, 4), 128, 0, stream>>>(X, W1, b1, ha, hb, ru);
  kB<<<dim3(16, 16, 4), 256, 0, stream>>>(ha, hb, C, W1, W2, b2, Km, ru);
  // Sinkhorn: fully fused cooperative kernel (10 iterations + adj epilogue)
  {
    void* args[] = {(void*)&Km, (void*)&ru, (void*)&rvpA, (void*)&rvpB, (void*)&adj};
    hipLaunchCooperativeKernel((void*)kSink, dim3(32, 4), dim3(512), args, 0, stream);
  }
  // GAT layer 0
  kG1<<<dim3(64, 4), 256, 0, stream>>>(X, Wg, xw);
  kG1b<<<dim3(512, 4), 128, 0, stream>>>(xw, as_, ad_, ssT, sdT);
  kG2t<<<dim3(64, 4, 4), 512, 0, stream>>>(xw, ssT, sdT, partial);
  kRed<<<256, 256, 0, stream>>>(partial, bg, x1);
  // GAT layer 1
  kG1<<<dim3(64, 4), 256, 0, stream>>>(x1, Wg + 65536, xw);
  kG1b<<<dim3(512, 4), 128, 0, stream>>>(xw, as_ + 512, ad_ + 512, ssT, sdT);
  kG2t<<<dim3(64, 4, 4), 512, 0, stream>>>(xw, ssT, sdT, partial);
  kRed<<<256, 256, 0, stream>>>(partial, bg + 128, x2);
  // final adjacency
  kF<<<dim3(16, 16, 4), 256, 0, stream>>>(x2, out);
}

// Round 6
// 216.099 us; speedup vs baseline: 1.7234x; 1.7234x over previous
//
#include <hip/hip_runtime.h>
#include <math.h>

#define NB 4
#define NN 512

// ---------------- kA: ha = X@Wa + b1, hb = X@Wb ; zero ru ----------------
__global__ void kA(const float* __restrict__ X, const float* __restrict__ W1,
                   const float* __restrict__ b1, float* __restrict__ ha,
                   float* __restrict__ hb, float* __restrict__ ru) {
  int b = blockIdx.y, n0 = blockIdx.x * 8;
  __shared__ float xs[8][128];
  int t = threadIdx.x;  // 128 threads
  for (int q = t; q < 1024; q += 128) {
    int r = q >> 7, f = q & 127;
    xs[r][f] = X[(size_t)(b * NN + n0 + r) * 128 + f];
  }
  int flat = b * 64 + blockIdx.x;
  if (flat < 16) ru[flat * 128 + t] = 0.f;
  __syncthreads();
  float accA[8] = {0,0,0,0,0,0,0,0}, accB[8] = {0,0,0,0,0,0,0,0};
  for (int f = 0; f < 128; ++f) {
    float wa = W1[f * 128 + t];
    float wb = W1[(128 + f) * 128 + t];
#pragma unroll
    for (int r = 0; r < 8; ++r) {
      accA[r] = fmaf(xs[r][f], wa, accA[r]);
      accB[r] = fmaf(xs[r][f], wb, accB[r]);
    }
  }
  float b1v = b1[t];
#pragma unroll
  for (int r = 0; r < 8; ++r) {
    ha[(size_t)(b * NN + n0 + r) * 128 + t] = accA[r] + b1v;
    hb[(size_t)(b * NN + n0 + r) * 128 + t] = accB[r];
  }
}

// ------- kB: K = exp(-5*cost), cost = relu(ha_i+hb_j+dist*wd)@W2 + b2 ----
__global__ void kB(const float* __restrict__ ha, const float* __restrict__ hb,
                   const float* __restrict__ coords, const float* __restrict__ W1,
                   const float* __restrict__ W2, const float* __restrict__ b2,
                   float* __restrict__ Km, float* __restrict__ ru) {
  int b = blockIdx.z, i0 = blockIdx.y * 32, j0 = blockIdx.x * 32;
  __shared__ alignas(16) float As[32][132];
  __shared__ alignas(16) float Bs[32][132];
  __shared__ alignas(16) float wd[128];
  __shared__ alignas(16) float w2[128];
  __shared__ float ci[32][3], cj[32][3];
  int t = threadIdx.x;  // 256
  for (int q = t; q < 1024; q += 256) {
    int r = q >> 5, c = (q & 31) * 4;
    *(float4*)&As[r][c] = *(const float4*)&ha[(size_t)(b * NN + i0 + r) * 128 + c];
    *(float4*)&Bs[r][c] = *(const float4*)&hb[(size_t)(b * NN + j0 + r) * 128 + c];
  }
  if (t < 128) { wd[t] = W1[256 * 128 + t]; w2[t] = W2[t]; }
  if (t < 96) ((float*)ci)[t] = coords[(size_t)(b * NN + i0) * 3 + t];
  else if (t < 192) ((float*)cj)[t - 96] = coords[(size_t)(b * NN + j0) * 3 + (t - 96)];
  __syncthreads();
  int tx = t & 15, ty = t >> 4;
  int ia = 2 * ty, ib = ia + 1, ja = tx, jb = tx + 16;
  float d00, d01, d10, d11;
  {
    float ax = ci[ia][0], ay = ci[ia][1], az = ci[ia][2];
    float bx = ci[ib][0], by = ci[ib][1], bz = ci[ib][2];
    float cx0 = cj[ja][0], cy0 = cj[ja][1], cz0 = cj[ja][2];
    float cx1 = cj[jb][0], cy1 = cj[jb][1], cz1 = cj[jb][2];
    float dx, dy, dz;
    dx = ax - cx0; dy = ay - cy0; dz = az - cz0;
    d00 = sqrtf(fmaxf(dx * dx + dy * dy + dz * dz, 0.f));
    dx = ax - cx1; dy = ay - cy1; dz = az - cz1;
    d01 = sqrtf(fmaxf(dx * dx + dy * dy + dz * dz, 0.f));
    dx = bx - cx0; dy = by - cy0; dz = bz - cz0;
    d10 = sqrtf(fmaxf(dx * dx + dy * dy + dz * dz, 0.f));
    dx = bx - cx1; dy = by - cy1; dz = bz - cz1;
    d11 = sqrtf(fmaxf(dx * dx + dy * dy + dz * dz, 0.f));
  }
  float a00 = 0, a01 = 0, a10 = 0, a11 = 0;
  for (int k = 0; k < 128; k += 4) {
    float4 A0 = *(float4*)&As[ia][k];
    float4 A1 = *(float4*)&As[ib][k];
    float4 B0 = *(float4*)&Bs[ja][k];
    float4 B1 = *(float4*)&Bs[jb][k];
    float4 W = *(float4*)&wd[k];
    float4 V = *(float4*)&w2[k];
#pragma unroll
    for (int kk = 0; kk < 4; ++kk) {
      float av = ((float*)&A0)[kk], av1 = ((float*)&A1)[kk];
      float bv = ((float*)&B0)[kk], bv1 = ((float*)&B1)[kk];
      float wv = ((float*)&W)[kk], vv = ((float*)&V)[kk];
      float t00 = fmaxf(fmaf(d00, wv, av + bv), 0.f);
      float t01 = fmaxf(fmaf(d01, wv, av + bv1), 0.f);
      float t10 = fmaxf(fmaf(d10, wv, av1 + bv), 0.f);
      float t11 = fmaxf(fmaf(d11, wv, av1 + bv1), 0.f);
      a00 = fmaf(t00, vv, a00);
      a01 = fmaf(t01, vv, a01);
      a10 = fmaf(t10, vv, a10);
      a11 = fmaf(t11, vv, a11);
    }
  }
  float b2v = b2[0];
  float k00 = __expf(-5.0f * (a00 + b2v));
  float k01 = __expf(-5.0f * (a01 + b2v));
  float k10 = __expf(-5.0f * (a10 + b2v));
  float k11 = __expf(-5.0f * (a11 + b2v));
  size_t r0 = (size_t)(b * NN + i0 + ia) * NN + j0;
  size_t r1 = (size_t)(b * NN + i0 + ib) * NN + j0;
  Km[r0 + ja] = k00; Km[r0 + jb] = k01;
  Km[r1 + ja] = k10; Km[r1 + jb] = k11;
  float s0 = k00 + k01, s1 = k10 + k11;
#pragma unroll
  for (int off = 1; off < 16; off <<= 1) {
    s0 += __shfl_xor(s0, off);
    s1 += __shfl_xor(s1, off);
  }
  if (tx == 0) {
    atomicAdd(&ru[b * NN + i0 + ia], s0);
    atomicAdd(&ru[b * NN + i0 + ib], s1);
  }
}

// ------- kCcol: rvp[ic] = partial col sums of K * (1/ru); 32-row slabs ---
__global__ __launch_bounds__(512) void kCcol(const float* __restrict__ Km,
                                             const float* __restrict__ ru,
                                             float* __restrict__ rvp) {
  int ic = blockIdx.x, b = blockIdx.y;  // ic < 16
  __shared__ float uinv[32];
  int t = threadIdx.x;  // 512
  if (t < 32) uinv[t] = 1.0f / ru[b * NN + ic * 32 + t];
  __syncthreads();
  const float* Kp = Km + (size_t)(b * NN + ic * 32) * NN + t;
  float acc = 0.f;
#pragma unroll 8
  for (int ii = 0; ii < 32; ++ii) acc = fmaf(Kp[(size_t)ii * NN], uinv[ii], acc);
  rvp[ic * 2048 + b * NN + t] = acc;
}

// ------- kCrc: fused Sinkhorn iteration (row pass + col partials) --------
__global__ __launch_bounds__(512) void kCrc(const float* __restrict__ Km,
                                            const float* __restrict__ rvpOld,
                                            float* __restrict__ rvpNew,
                                            float* __restrict__ ru) {
  int ic = blockIdx.x, b = blockIdx.y;  // (16, 4)
  __shared__ float vinv[512];
  __shared__ float uinv[32];
  int t = threadIdx.x;  // 512
  {
    float s = 0.f;
#pragma unroll
    for (int q = 0; q < 16; ++q) s += rvpOld[q * 2048 + b * NN + t];
    vinv[t] = 1.0f / s;
  }
  __syncthreads();
  int w = t >> 6, l = t & 63;  // 8 waves, 4 rows each
#pragma unroll
  for (int m = 0; m < 4; ++m) {
    int r = ic * 32 + w * 4 + m;
    const float* Kp = Km + (size_t)(b * NN + r) * NN;
    float acc = 0.f;
#pragma unroll
    for (int mm = 0; mm < 8; ++mm) acc = fmaf(Kp[l + 64 * mm], vinv[l + 64 * mm], acc);
#pragma unroll
    for (int off = 1; off < 64; off <<= 1) acc += __shfl_xor(acc, off);
    if (l == 0) { uinv[w * 4 + m] = 1.0f / acc; ru[b * NN + r] = acc; }
  }
  __syncthreads();
  {
    const float* Kp = Km + (size_t)(b * NN + ic * 32) * NN + t;
    float acc = 0.f;
#pragma unroll 8
    for (int ii = 0; ii < 32; ++ii) acc = fmaf(Kp[(size_t)ii * NN], uinv[ii], acc);
    rvpNew[ic * 2048 + b * NN + t] = acc;
  }
}

// ------- kAdj: adj = (1/ru_i) * K * (1/rv_j) -----------------------------
__global__ __launch_bounds__(512) void kAdj(const float* __restrict__ Km,
                                            const float* __restrict__ ru,
                                            const float* __restrict__ rvp,
                                            float* __restrict__ out) {
  int rc = blockIdx.x, b = blockIdx.y;  // (16, 4)
  __shared__ float vinv[512];
  __shared__ float uinv[32];
  int t = threadIdx.x;  // 512
  {
    float s = 0.f;
#pragma unroll
    for (int ic = 0; ic < 16; ++ic) s += rvp[ic * 2048 + b * NN + t];
    vinv[t] = 1.0f / s;
  }
  if (t < 32) uinv[t] = 1.0f / ru[b * NN + rc * 32 + t];
  __syncthreads();
  float vj = vinv[t];
  const float* Kp = Km + (size_t)(b * NN + rc * 32) * NN + t;
  float* op = out + (size_t)(b * NN + rc * 32) * NN + t;
#pragma unroll 4
  for (int m = 0; m < 32; ++m) {
    op[(size_t)m * NN] = Kp[(size_t)m * NN] * uinv[m] * vj;
  }
}

// ------- kG1f: xw = x @ Wg[l] + fused s_src/s_dst epilogue ---------------
__global__ void kG1f(const float* __restrict__ x, const float* __restrict__ Wg,
                     const float* __restrict__ asrc, const float* __restrict__ adst,
                     float* __restrict__ xw, float* __restrict__ ssT,
                     float* __restrict__ sdT) {
  int b = blockIdx.y, n0 = blockIdx.x * 8;
  __shared__ float xs[8][128];
  __shared__ float red[4][8][4];  // wave, r, {s_c0, d_c0, s_c1, d_c1}
  int t = threadIdx.x;  // 256
  for (int q = t; q < 1024; q += 256) {
    int r = q >> 7, f = q & 127;
    xs[r][f] = x[(size_t)(b * NN + n0 + r) * 128 + f];
  }
  __syncthreads();
  int c0 = t, c1 = t + 256;
  float acc0[8] = {0,0,0,0,0,0,0,0}, acc1[8] = {0,0,0,0,0,0,0,0};
  for (int f = 0; f < 128; ++f) {
    float w0 = Wg[f * 512 + c0], w1 = Wg[f * 512 + c1];
#pragma unroll
    for (int r = 0; r < 8; ++r) {
      float xv = xs[r][f];
      acc0[r] = fmaf(xv, w0, acc0[r]);
      acc1[r] = fmaf(xv, w1, acc1[r]);
    }
  }
#pragma unroll
  for (int r = 0; r < 8; ++r) {
    xw[(size_t)(b * NN + n0 + r) * 512 + c0] = acc0[r];
    xw[(size_t)(b * NN + n0 + r) * 512 + c1] = acc1[r];
  }
  // fused attention-logit projections: s = sum_f xw[n,h,f]*a[h,f]
  float as0 = asrc[c0], ad0 = adst[c0];
  float as1 = asrc[c1], ad1 = adst[c1];
  int w = t >> 6, l = t & 63;
#pragma unroll
  for (int r = 0; r < 8; ++r) {
    float ps0 = acc0[r] * as0, pd0 = acc0[r] * ad0;
    float ps1 = acc1[r] * as1, pd1 = acc1[r] * ad1;
#pragma unroll
    for (int off = 1; off < 64; off <<= 1) {
      ps0 += __shfl_xor(ps0, off);
      pd0 += __shfl_xor(pd0, off);
      ps1 += __shfl_xor(ps1, off);
      pd1 += __shfl_xor(pd1, off);
    }
    if (l == 0) {
      red[w][r][0] = ps0; red[w][r][1] = pd0;
      red[w][r][2] = ps1; red[w][r][3] = pd1;
    }
  }
  __syncthreads();
  if (t < 64) {
    // waves 0,1 cover t<128 (h=0 for c0, h=2 for c1); waves 2,3 cover h=1,3
    int r = t & 7, h = (t >> 3) & 3, sd = t >> 5;
    int wbase = (h & 1) ? 2 : 0;
    int which = (h < 2 ? 0 : 2) + sd;
    float s = red[wbase][r][which] + red[wbase + 1][r][which];
    float* dst = sd ? sdT : ssT;
    dst[(size_t)(b * 4 + h) * 512 + n0 + r] = s;
  }
}

// ------- kG2t: per (b,h,8-row tile): P in LDS + 4-way j-split PV ---------
#define PLD8 520
__global__ __launch_bounds__(512) void kG2t(const float* __restrict__ xw,
                                            const float* __restrict__ ssT,
                                            const float* __restrict__ sdT,
                                            float* __restrict__ partial) {
  int b = blockIdx.z, h = blockIdx.y, i0 = blockIdx.x * 8;
  int bh = b * 4 + h;
  __shared__ float ss[512];
  __shared__ alignas(16) float pl[8][PLD8];   // reused as reduce scratch
  __shared__ float sdl[8], mxl[8], idl[8], smaxsh[8];
  int t = threadIdx.x;  // 512
  {
    float v = ssT[(size_t)bh * 512 + t];
    ss[t] = v;
#pragma unroll
    for (int off = 1; off < 64; off <<= 1) v = fmaxf(v, __shfl_xor(v, off));
    if ((t & 63) == 0) smaxsh[t >> 6] = v;
  }
  __syncthreads();
  if (t < 8) {
    float m = smaxsh[0];
#pragma unroll
    for (int q = 1; q < 8; ++q) m = fmaxf(m, smaxsh[q]);
    float sdv = sdT[(size_t)bh * 512 + i0 + t];
    sdl[t] = sdv;
    float mm = sdv + m;
    mxl[t] = (mm >= 0.f) ? mm : 0.2f * mm;
  }
  __syncthreads();
  {
    int il = t >> 6, jq = t & 63;
    float mx = mxl[il], sdv = sdl[il];
    float den = 0.f;
#pragma unroll
    for (int jj = 0; jj < 8; ++jj) {
      int j = jj * 64 + jq;
      float e = sdv + ss[j];
      e = (e >= 0.f) ? e : 0.2f * e;
      float pe = __expf(e - mx);
      pl[il][j] = pe;
      den += pe;
    }
#pragma unroll
    for (int off = 1; off < 64; off <<= 1) den += __shfl_xor(den, off);
    if (jq == 0) idl[il] = 1.0f / (4.0f * den);
  }
  __syncthreads();
  int fq = t & 31, rr = (t >> 5) & 3, jh = t >> 7;
  const float* xp = xw + (size_t)(b * NN) * 512 + h * 128 + fq * 4;
  float4 a0 = {0,0,0,0}, a1 = {0,0,0,0};
  int jbase = jh * 128;
#pragma unroll 4
  for (int jj = 0; jj < 128; jj += 2) {
    int j = jbase + jj;
    float4 xv0 = *(const float4*)&xp[(size_t)j * 512];
    float4 xv1 = *(const float4*)&xp[(size_t)(j + 1) * 512];
    float2 p0 = *(const float2*)&pl[rr][j];
    float2 p1 = *(const float2*)&pl[rr + 4][j];
    a0.x = fmaf(p0.x, xv0.x, a0.x); a0.y = fmaf(p0.x, xv0.y, a0.y);
    a0.z = fmaf(p0.x, xv0.z, a0.z); a0.w = fmaf(p0.x, xv0.w, a0.w);
    a1.x = fmaf(p1.x, xv0.x, a1.x); a1.y = fmaf(p1.x, xv0.y, a1.y);
    a1.z = fmaf(p1.x, xv0.z, a1.z); a1.w = fmaf(p1.x, xv0.w, a1.w);
    a0.x = fmaf(p0.y, xv1.x, a0.x); a0.y = fmaf(p0.y, xv1.y, a0.y);
    a0.z = fmaf(p0.y, xv1.z, a0.z); a0.w = fmaf(p0.y, xv1.w, a0.w);
    a1.x = fmaf(p1.y, xv1.x, a1.x); a1.y = fmaf(p1.y, xv1.y, a1.y);
    a1.z = fmaf(p1.y, xv1.z, a1.z); a1.w = fmaf(p1.y, xv1.w, a1.w);
  }
  __syncthreads();
  float4* sc4 = (float4*)pl;
  sc4[(rr * 32 + fq) + 256 * jh] = a0;
  sc4[((rr + 4) * 32 + fq) + 256 * jh] = a1;
  __syncthreads();
  if (t < 256) {
    int r = t >> 5, ff = t & 31;
    float4 u0 = sc4[(r * 32 + ff)];
    float4 u1 = sc4[(r * 32 + ff) + 256];
    float4 u2 = sc4[(r * 32 + ff) + 512];
    float4 u3 = sc4[(r * 32 + ff) + 768];
    float s0 = idl[r];
    float4 o;
    o.x = (u0.x + u1.x + u2.x + u3.x) * s0;
    o.y = (u0.y + u1.y + u2.y + u3.y) * s0;
    o.z = (u0.z + u1.z + u2.z + u3.z) * s0;
    o.w = (u0.w + u1.w + u2.w + u3.w) * s0;
    *(float4*)&partial[((size_t)bh * NN + i0 + r) * 128 + ff * 4] = o;
  }
}

// ------- kRed: xo[b,i,f] = sum_h partial[b,h,i,f] + bg[f] ----------------
__global__ void kRed(const float* __restrict__ partial, const float* __restrict__ bg,
                     float* __restrict__ xo) {
  int idx = blockIdx.x * 256 + threadIdx.x;  // float4 index, 65536 total
  int f4 = idx & 31;
  int rest = idx >> 5;           // b*512 + i
  int b = rest >> 9, i = rest & 511;
  const float* pp = partial + (((size_t)b * 4) * NN + i) * 128 + f4 * 4;
  float4 s = *(const float4*)pp;
  const float* p1 = pp + (size_t)NN * 128;
  const float* p2 = pp + (size_t)2 * NN * 128;
  const float* p3 = pp + (size_t)3 * NN * 128;
  float4 v1 = *(const float4*)p1, v2 = *(const float4*)p2, v3 = *(const float4*)p3;
  float4 bb = *(const float4*)&bg[f4 * 4];
  s.x += v1.x + v2.x + v3.x + bb.x;
  s.y += v1.y + v2.y + v3.y + bb.y;
  s.z += v1.z + v2.z + v3.z + bb.z;
  s.w += v1.w + v2.w + v3.w + bb.w;
  *(float4*)&xo[(size_t)rest * 128 + f4 * 4] = s;
}

// ------- kF: final_adj = sigmoid(x @ x^T) --------------------------------
__global__ void kF(const float* __restrict__ x, float* __restrict__ out) {
  int b = blockIdx.z, i0 = blockIdx.y * 32, j0 = blockIdx.x * 32;
  __shared__ alignas(16) float As[32][132];
  __shared__ alignas(16) float Bs[32][132];
  int t = threadIdx.x;  // 256
  for (int q = t; q < 1024; q += 256) {
    int r = q >> 5, c = (q & 31) * 4;
    *(float4*)&As[r][c] = *(const float4*)&x[(size_t)(b * NN + i0 + r) * 128 + c];
    *(float4*)&Bs[r][c] = *(const float4*)&x[(size_t)(b * NN + j0 + r) * 128 + c];
  }
  __syncthreads();
  int tx = t & 15, ty = t >> 4;
  int ia = 2 * ty, ib = ia + 1, ja = tx, jb = tx + 16;
  float a00 = 0, a01 = 0, a10 = 0, a11 = 0;
  for (int k = 0; k < 128; k += 4) {
    float4 A0 = *(float4*)&As[ia][k];
    float4 A1 = *(float4*)&As[ib][k];
    float4 B0 = *(float4*)&Bs[ja][k];
    float4 B1 = *(float4*)&Bs[jb][k];
#pragma unroll
    for (int kk = 0; kk < 4; ++kk) {
      float av = ((float*)&A0)[kk], av1 = ((float*)&A1)[kk];
      float bv = ((float*)&B0)[kk], bv1 = ((float*)&B1)[kk];
      a00 = fmaf(av, bv, a00);
      a01 = fmaf(av, bv1, a01);
      a10 = fmaf(av1, bv, a10);
      a11 = fmaf(av1, bv1, a11);
    }
  }
  size_t r0 = (size_t)(b * NN + i0 + ia) * NN + j0;
  size_t r1 = (size_t)(b * NN + i0 + ib) * NN + j0;
  out[r0 + ja] = 1.0f / (1.0f + __expf(-a00));
  out[r0 + jb] = 1.0f / (1.0f + __expf(-a01));
  out[r1 + ja] = 1.0f / (1.0f + __expf(-a10));
  out[r1 + jb] = 1.0f / (1.0f + __expf(-a11));
}

extern "C" void kernel_launch(void* const* d_in, const int* in_sizes, int n_in,
                              void* d_out, int out_size, void* d_ws, size_t ws_size,
                              hipStream_t stream) {
  (void)in_sizes; (void)n_in; (void)out_size; (void)ws_size;
  const float* X   = (const float*)d_in[0];
  const float* C   = (const float*)d_in[1];
  const float* W1  = (const float*)d_in[2];
  const float* b1  = (const float*)d_in[3];
  const float* W2  = (const float*)d_in[4];
  const float* b2  = (const float*)d_in[5];
  const float* Wg  = (const float*)d_in[6];
  const float* as_ = (const float*)d_in[7];
  const float* ad_ = (const float*)d_in[8];
  const float* bg  = (const float*)d_in[9];
  float* out = (float*)d_out;
  float* ws = (float*)d_ws;

  float* ha    = ws;                 // 262144
  float* hb    = ws + 262144;        // 262144
  float* Km    = ws + 524288;        // 1048576
  float* ru    = ws + 1572864;       // 2048
  float* xw    = ws + 1591296;       // 1048576
  float* ssT   = ws + 2639872;       // 8192
  float* sdT   = ws + 2648064;       // 8192
  float* x1    = ws + 2656256;       // 262144
  float* x2    = ws + 2918400;       // 262144
  float* rvpA  = ws + 3180544;       // 32768 (16 slabs x 4 b x 512 j)
  float* rvpB  = ws + 3246080;       // 32768
  float* adj   = out + 1048576;
  float* partial = Km;               // alias: Km is dead after kAdj

  kA<<<dim3(64, 4), 128, 0, stream>>>(X, W1, b1, ha, hb, ru);
  kB<<<dim3(16, 16, 4), 256, 0, stream>>>(ha, hb, C, W1, W2, b2, Km, ru);
  // Sinkhorn: kB produced ru (row sums); kCcol -> rvpA; 9 fused iterations
  kCcol<<<dim3(16, 4), 512, 0, stream>>>(Km, ru, rvpA);
  for (int it = 0; it < 9; ++it) {
    const float* src = (it & 1) ? rvpB : rvpA;
    float* dst = (it & 1) ? rvpA : rvpB;
    kCrc<<<dim3(16, 4), 512, 0, stream>>>(Km, src, dst, ru);
  }
  kAdj<<<dim3(16, 4), 512, 0, stream>>>(Km, ru, rvpB, adj);
  // GAT layer 0
  kG1f<<<dim3(64, 4), 256, 0, stream>>>(X, Wg, as_, ad_, xw, ssT, sdT);
  kG2t<<<dim3(64, 4, 4), 512, 0, stream>>>(xw, ssT, sdT, partial);
  kRed<<<256, 256, 0, stream>>>(partial, bg, x1);
  // GAT layer 1
  kG1f<<<dim3(64, 4), 256, 0, stream>>>(x1, Wg + 65536, as_ + 512, ad_ + 512, xw, ssT, sdT);
  kG2t<<<dim3(64, 4, 4), 512, 0, stream>>>(xw, ssT, sdT, partial);
  kRed<<<256, 256, 0, stream>>>(partial, bg + 128, x2);
  // final adjacency
  kF<<<dim3(16, 16, 4), 256, 0, stream>>>(x2, out);
}